// Round 8
// baseline (254.647 us; speedup 1.0000x reference)
//
#include <hip/hip_runtime.h>
#include <hip/hip_bf16.h>
#include <math.h>

#define BB 8
#define CCH 256          // channels
#define NN 2304          // H*W
#define NH 4
#define HDIM 64
#define QKV_ROWS 384
#define BN_EPS 1e-5f
#define NTILES 36        // NN / 64
#define NPART 288        // BB * 36 proj blocks contributing per channel
// scale folded into q weights: 1/sqrt(64) * log2(e)  -> attention uses exp2
#define SLOG2E 0.18033688011112042f

typedef short bf16x8 __attribute__((ext_vector_type(8)));
typedef short bf16x4 __attribute__((ext_vector_type(4)));
typedef float f32x4 __attribute__((ext_vector_type(4)));

#if __has_builtin(__builtin_amdgcn_exp2f)
#define EXP2(x) __builtin_amdgcn_exp2f(x)
#else
#define EXP2(x) __expf((x) * 0.6931471805599453f)
#endif

#define MFMA32(a, b, c) __builtin_amdgcn_mfma_f32_16x16x32_bf16(a, b, c, 0, 0, 0)

__device__ __forceinline__ unsigned bfpair(float a, float b) {
    __hip_bfloat162 h = __float22bfloat162_rn(make_float2(a, b));
    return *(unsigned*)&h;
}
__device__ __forceinline__ unsigned short f2bf(float f) {
    unsigned u = __float_as_uint(f);
    u = (u + 0x7FFFu + ((u >> 16) & 1u)) >> 16;
    return (unsigned short)u;
}
__device__ __forceinline__ float bf2f(unsigned short s) {
    return __uint_as_float((unsigned)s << 16);
}

// ---------------------------------------------------------------------------
// K0: prep — x-transpose/convert (+bf16 residual copy xb) + weight convert.
// ---------------------------------------------------------------------------
__global__ __launch_bounds__(256) void prep_k(
    const float* __restrict__ x,
    const float* __restrict__ qw, const float* __restrict__ kw,
    const float* __restrict__ vw, const float* __restrict__ pw,
    unsigned short* __restrict__ xT, unsigned short* __restrict__ xb,
    unsigned short* __restrict__ Wb, unsigned short* __restrict__ Pb)
{
    const int bid = blockIdx.x;
    const int tid = threadIdx.x;
    if (bid < 1152) {
        __shared__ float sX[64][65];
        const int b  = bid / 144;
        const int rem = bid - b * 144;
        const int nb = (rem >> 2) * 64;
        const int cb = (rem & 3) * 64;

        #pragma unroll
        for (int u = 0; u < 4; ++u) {
            int c  = (tid >> 4) + 16 * u;
            int n4 = (tid & 15) * 4;
            float4 v = *(const float4*)(x + ((size_t)(b * CCH + cb + c)) * NN + nb + n4);
            sX[c][n4+0] = v.x; sX[c][n4+1] = v.y; sX[c][n4+2] = v.z; sX[c][n4+3] = v.w;
        }
        __syncthreads();

        // xT[b][n][c] (transposed)
        const int n  = tid >> 2;
        const int cg = (tid & 3) * 16;
        unsigned vals[8];
        #pragma unroll
        for (int p = 0; p < 8; ++p)
            vals[p] = bfpair(sX[cg + 2*p][n], sX[cg + 2*p + 1][n]);
        unsigned short* dst = xT + ((size_t)(b * NN + nb + n)) * CCH + cb + cg;
        *(uint4*)dst = make_uint4(vals[0], vals[1], vals[2], vals[3]);
        *(uint4*)(dst + 8) = make_uint4(vals[4], vals[5], vals[6], vals[7]);

        // xb[b][c][n] (same layout as x, bf16) — for bn_apply residual
        #pragma unroll
        for (int it = 0; it < 2; ++it) {
            int flat = tid + 256 * it;      // 0..511
            int row = flat >> 3;            // c local
            int n8  = (flat & 7) * 8;
            unsigned vv[4];
            #pragma unroll
            for (int p = 0; p < 4; ++p)
                vv[p] = bfpair(sX[row][n8 + 2*p], sX[row][n8 + 2*p + 1]);
            *(uint4*)(xb + ((size_t)(b * CCH + cb + row)) * NN + nb + n8) =
                make_uint4(vv[0], vv[1], vv[2], vv[3]);
        }
    } else {
        int idx = (bid - 1152) * 256 + tid;
        if (idx < 98304) {
            int o = idx >> 8, c = idx & 255;
            float v;
            if (o < 256)      v = qw[(size_t)o * CCH + c] * SLOG2E;
            else if (o < 320) v = kw[(size_t)(o - 256) * CCH + c];
            else              v = vw[(size_t)(o - 320) * CCH + c];
            Wb[idx] = f2bf(v);
        } else {
            int j = idx - 98304;
            if (j < 65536) Pb[j] = f2bf(pw[j]);
        }
    }
}

// ---------------------------------------------------------------------------
// K1: qkv MFMA GEMM, K-loop software-pipelined (round-11/13 verified 64x64).
// grid (8 b, 36 ntile, 3 otile), 128 thr (2 waves).
//   Qt[b][n][256] (q pre-scaled), Kt[b][n][64], Vn[b][64][n], all bf16.
// ---------------------------------------------------------------------------
__global__ __launch_bounds__(128) void qkv_mfma_k(
    const unsigned short* __restrict__ Wb, const unsigned short* __restrict__ xT,
    unsigned short* __restrict__ Qt, unsigned short* __restrict__ Kt,
    unsigned short* __restrict__ Vn)
{
    __shared__ unsigned short sE[2][64 * 72];
    const int tid = threadIdx.x;
    const int wave = tid >> 6;
    const int lane = tid & 63;
    const int quad = lane >> 4;
    const int l15  = lane & 15;
    const int b  = blockIdx.x;
    const int nb = blockIdx.y * 64;
    const int mb = blockIdx.z * 128 + wave * 64;

    const unsigned short* Ab = Wb + (size_t)(mb + l15) * CCH + quad * 8;
    const unsigned short* Bb = xT + ((size_t)(b * NN + nb + l15)) * CCH + quad * 8;

    f32x4 C[4][4] = {};
    bf16x8 aA[2][4], bB[2][4];
    #pragma unroll
    for (int i = 0; i < 4; ++i) aA[0][i] = *(const bf16x8*)(Ab + (size_t)(16*i) * CCH);
    #pragma unroll
    for (int j = 0; j < 4; ++j) bB[0][j] = *(const bf16x8*)(Bb + (size_t)(16*j) * CCH);

    #pragma unroll
    for (int kk = 0; kk < 8; ++kk) {
        const int cur = kk & 1;
        if (kk < 7) {
            const int k1 = (kk + 1) * 32;
            #pragma unroll
            for (int i = 0; i < 4; ++i) aA[cur^1][i] = *(const bf16x8*)(Ab + (size_t)(16*i) * CCH + k1);
            #pragma unroll
            for (int j = 0; j < 4; ++j) bB[cur^1][j] = *(const bf16x8*)(Bb + (size_t)(16*j) * CCH + k1);
        }
        #pragma unroll
        for (int i = 0; i < 4; ++i)
            #pragma unroll
            for (int j = 0; j < 4; ++j)
                C[i][j] = MFMA32(aA[cur][i], bB[cur][j], C[i][j]);
    }

    unsigned short* sEw = &sE[wave][0];
    if (mb < 320) {
        // Q or K: transpose to [n][o] rows
        #pragma unroll
        for (int i = 0; i < 4; ++i)
            #pragma unroll
            for (int j = 0; j < 4; ++j) {
                unsigned p01 = bfpair(C[i][j][0], C[i][j][1]);
                unsigned p23 = bfpair(C[i][j][2], C[i][j][3]);
                unsigned short* p = sEw + (16*j + l15) * 72 + 16*i + quad*4;
                *(unsigned*)p = p01;
                *(unsigned*)(p + 2) = p23;
            }
        if (mb < 256) {
            #pragma unroll
            for (int it = 0; it < 8; ++it) {
                int flat = lane + 64 * it;
                int row = flat >> 3;
                int o8  = (flat & 7) * 8;
                uint4 v = *(const uint4*)(sEw + row * 72 + o8);
                *(uint4*)(Qt + ((size_t)(b * NN + nb + row)) * CCH + mb + o8) = v;
            }
        } else {
            #pragma unroll
            for (int it = 0; it < 8; ++it) {
                int flat = lane + 64 * it;
                int row = flat >> 3;
                int o8  = (flat & 7) * 8;
                uint4 v = *(const uint4*)(sEw + row * 72 + o8);
                *(uint4*)(Kt + ((size_t)(b * NN + nb + row)) * 64 + o8) = v;
            }
        }
    } else {
        // V: [d][n] rows
        #pragma unroll
        for (int i = 0; i < 4; ++i)
            #pragma unroll
            for (int j = 0; j < 4; ++j) {
                unsigned p01 = bfpair(C[i][j][0], C[i][j][1]);
                unsigned p23 = bfpair(C[i][j][2], C[i][j][3]);
                unsigned short* p = sEw + (16*i + quad*4) * 72 + 16*j + l15;
                p[0]   = (unsigned short)p01;
                p[72]  = (unsigned short)(p01 >> 16);
                p[144] = (unsigned short)p23;
                p[216] = (unsigned short)(p23 >> 16);
            }
        #pragma unroll
        for (int it = 0; it < 8; ++it) {
            int flat = lane + 64 * it;
            int row = flat >> 3;
            int n8  = (flat & 7) * 8;
            uint4 v = *(const uint4*)(sEw + row * 72 + n8);
            *(uint4*)(Vn + ((size_t)(b * 64 + (mb - 320) + row)) * NN + nb + n8) = v;
        }
    }
}

// ---------------------------------------------------------------------------
// K2: MFMA attention — round-24: SINGLE-WAVE blocks, ZERO main-loop barriers.
// Evidence from r17-r23: five configs (18/36 steps, 2-8 waves, 32-64KB LDS,
// +-deferred-PV, +-setprio) all cost ~4000 cyc per K-tile vs ~250-900 issue
// cycles. The never-varied invariant: the per-step __syncthreads rhythm (all
// waves drain vmcnt/lgkmcnt + rendezvous each step; ~1.3 blocks/CU can't
// cover the serialized phases). Fix: one 64-thread wave owns (b, head, 64
// queries); LDS produced+consumed by the SAME wave needs no barrier at all —
// compiler's lgkmcnt/vmcnt tracking gives exact ordering. QW=64 keeps the
// best MFMA:LDS ratio (aK/aV fragments feed 4 q-tiles); bP is step-local (no
// ping-pong regs). Two-phase staging via pf[8]: write K[s+1] -> issue V[s+1]
// loads -> QK+exp2 (covers V latency) -> write V[s+1] -> issue K[s+2] ->
// dacc+PV. sigma-permuted K rows + XOR swizzles + accumulation order are
// byte-identical per query to r20.
// Grid 1152 blocks x 32KB LDS -> 5 blocks/CU capacity >= 4.5 needed: all
// co-resident. VGPR peak ~220 (bQ32+O64+dacc16+pf32+C32+bP32+addr) < 256.
// Spill tripwire: WRITE_SIZE must stay ~9.2MB (r22's spill showed as 63MB).
// ---------------------------------------------------------------------------
__global__ __launch_bounds__(64) void attn_k(
    const unsigned short* __restrict__ Qt,  // [B][N][256]
    const unsigned short* __restrict__ Kt,  // [B][N][64]
    const unsigned short* __restrict__ Vn,  // [B][64][N]
    unsigned short* __restrict__ Ao)        // [B][N][256]
{
    // 2 phases x (4096 K + 4096 V) shorts = 32 KB, XOR-swizzled, K sigma-rows
    __shared__ __align__(16) unsigned short sKV[16384];

    const int lane = threadIdx.x;    // 0..63
    const int quad = lane >> 4;
    const int l15  = lane & 15;
    const int nb   = blockIdx.x * 64;
    const int head = blockIdx.y;
    const int b    = blockIdx.z;

    const bf16x8 vone8 = {(short)0x3F80, (short)0x3F80, (short)0x3F80, (short)0x3F80,
                          (short)0x3F80, (short)0x3F80, (short)0x3F80, (short)0x3F80};

    // Q fragments (B-operand for S^T): B[n=query][k=d=quad*8+j], 4 q-tiles
    bf16x8 bQ[4][2];
    const unsigned short* QtB = Qt + ((size_t)(b * NN + nb + l15)) * CCH + head * 64 + quad * 8;
    #pragma unroll
    for (int qt = 0; qt < 4; ++qt)
        #pragma unroll
        for (int s = 0; s < 2; ++s)
            bQ[qt][s] = *(const bf16x8*)(QtB + (size_t)(16*qt) * CCH + s * 32);

    // staging geometry: 64 lanes x 8 chunks per 8KB tile
    const int r0 = lane >> 3;        // 0..7
    const int j8 = (lane & 7) * 8;   // source column (bytes/2)
    const int vwc = ((lane & 7) ^ r0) * 8;   // V write col (row&7 == r0 for all u)
    const unsigned short* Kp = Kt + (size_t)b * NN * 64;
    const unsigned short* Vp = Vn + (size_t)b * 64 * NN;

    bf16x8 pf[8];

    // prologue: K[0] -> buf0
    #pragma unroll
    for (int u = 0; u < 8; ++u)
        pf[u] = *(const bf16x8*)(Kp + (size_t)(r0 + 8*u) * 64 + j8);
    #pragma unroll
    for (int u = 0; u < 8; ++u) {
        const int row = r0 + 8*u;
        const int kr  = (row & 3) | (((row >> 3) & 3) << 2) | (((row >> 2) & 1) << 4) | (row & 32);
        *(bf16x8*)(sKV + kr * 64 + ((lane & 7) ^ (kr & 7)) * 8) = pf[u];
    }
    // V[0] -> buf0
    #pragma unroll
    for (int u = 0; u < 8; ++u)
        pf[u] = *(const bf16x8*)(Vp + (size_t)(r0 + 8*u) * NN + j8);
    #pragma unroll
    for (int u = 0; u < 8; ++u)
        *(bf16x8*)(sKV + 4096 + (r0 + 8*u) * 64 + vwc) = pf[u];
    // issue K[1] loads
    #pragma unroll
    for (int u = 0; u < 8; ++u)
        pf[u] = *(const bf16x8*)(Kp + (size_t)(64 + r0 + 8*u) * 64 + j8);

    f32x4 O[4][4] = {};          // O^T[d-tile jd][q-tile qt]
    f32x4 dacc[4] = {};          // softmax denominators via ones-MFMA

    for (int step = 0; step < NTILES; ++step) {
        const int cur = (step & 1) * 8192;
        const int nxt = 8192 - cur;

        // a) write K[step+1] into other phase (vmcnt waits on phase-d loads)
        if (step + 1 < NTILES) {
            #pragma unroll
            for (int u = 0; u < 8; ++u) {
                const int row = r0 + 8*u;
                const int kr  = (row & 3) | (((row >> 3) & 3) << 2) | (((row >> 2) & 1) << 4) | (row & 32);
                *(bf16x8*)(sKV + nxt + kr * 64 + ((lane & 7) ^ (kr & 7)) * 8) = pf[u];
            }
            // b) issue V[step+1] loads (latency covered by QK+exp2 below)
            const int k1 = (step + 1) * 64;
            #pragma unroll
            for (int u = 0; u < 8; ++u)
                pf[u] = *(const bf16x8*)(Vp + (size_t)(r0 + 8*u) * NN + k1 + j8);
        }

        // c) S^T = K.Q^T per kt2-pair, exp2 -> bf16 B-fragments (lane-local)
        bf16x8 bP[2][4];
        #pragma unroll
        for (int kt2 = 0; kt2 < 2; ++kt2) {
            f32x4 C[2][4] = {};
            #pragma unroll
            for (int s = 0; s < 2; ++s)
                #pragma unroll
                for (int kth = 0; kth < 2; ++kth) {
                    const int row = 16 * (2*kt2 + kth) + l15;
                    const int chsw = ((s*4 + quad) ^ (row & 7)) * 8;
                    bf16x8 aK = *(const bf16x8*)(sKV + cur + row * 64 + chsw);
                    #pragma unroll
                    for (int qt = 0; qt < 4; ++qt)
                        C[kth][qt] = MFMA32(aK, bQ[qt][s], C[kth][qt]);
                }
            #pragma unroll
            for (int qt = 0; qt < 4; ++qt) {
                union { unsigned u[4]; bf16x8 v; } xp;
                const f32x4 c0 = C[0][qt];
                const f32x4 c1 = C[1][qt];
                xp.u[0] = bfpair(EXP2(c0[0]), EXP2(c0[1]));
                xp.u[1] = bfpair(EXP2(c0[2]), EXP2(c0[3]));
                xp.u[2] = bfpair(EXP2(c1[0]), EXP2(c1[1]));
                xp.u[3] = bfpair(EXP2(c1[2]), EXP2(c1[3]));
                bP[kt2][qt] = xp.v;
            }
        }

        // d) write V[step+1]; issue K[step+2] loads
        if (step + 1 < NTILES) {
            #pragma unroll
            for (int u = 0; u < 8; ++u)
                *(bf16x8*)(sKV + nxt + 4096 + (r0 + 8*u) * 64 + vwc) = pf[u];
        }
        if (step + 2 < NTILES) {
            const int k2 = (step + 2) * 64;
            #pragma unroll
            for (int u = 0; u < 8; ++u)
                pf[u] = *(const bf16x8*)(Kp + (size_t)(k2 + r0 + 8*u) * 64 + j8);
        }

        // e) denominators on the matrix pipe
        #pragma unroll
        for (int kt2 = 0; kt2 < 2; ++kt2)
            #pragma unroll
            for (int qt = 0; qt < 4; ++qt)
                dacc[qt] = MFMA32(vone8, bP[kt2][qt], dacc[qt]);

        // f) O^T += V . P^T (aV fragments shared across all 4 q-tiles)
        #pragma unroll
        for (int jd = 0; jd < 4; ++jd)
            #pragma unroll
            for (int kt2 = 0; kt2 < 2; ++kt2) {
                const int row = 16*jd + l15;
                const int chsw = ((4*kt2 + quad) ^ (row & 7)) * 8;
                bf16x8 aV = *(const bf16x8*)(sKV + cur + 4096 + row * 64 + chsw);
                #pragma unroll
                for (int qt = 0; qt < 4; ++qt)
                    O[jd][qt] = MFMA32(aV, bP[kt2][qt], O[jd][qt]);
            }
    }
    __syncthreads();   // single wave: cheap; orders LDS reuse for sT overlay

    // normalize + transpose to [query][d] rows via LDS
    float rinv[4];
    #pragma unroll
    for (int qt = 0; qt < 4; ++qt)
        rinv[qt] = 1.0f / dacc[qt][0];
    unsigned short* sT = (unsigned short*)sKV;   // [64 n][72]
    #pragma unroll
    for (int qt = 0; qt < 4; ++qt)
        #pragma unroll
        for (int jd = 0; jd < 4; ++jd) {
            unsigned lo = bfpair(O[jd][qt][0] * rinv[qt], O[jd][qt][1] * rinv[qt]);
            unsigned hi = bfpair(O[jd][qt][2] * rinv[qt], O[jd][qt][3] * rinv[qt]);
            *(uint2*)(sT + (16*qt + l15) * 72 + 16*jd + quad*4) = make_uint2(lo, hi);
        }
    __syncthreads();

    // coalesced writeout: 64 rows x 64 channels = 512 uint4 chunks
    #pragma unroll
    for (int it = 0; it < 8; ++it) {
        int flat = lane + 64 * it;          // 0..511
        int row  = flat >> 3;               // 0..63
        int cc8  = (flat & 7) * 8;
        uint4 v = *(const uint4*)(sT + row * 72 + cc8);
        *(uint4*)(Ao + ((size_t)(b * NN + nb + row)) * CCH + head * 64 + cc8) = v;
    }
}

// ---------------------------------------------------------------------------
// K3: proj MFMA GEMM (64x64 pipelined) + per-block BN partials.
// projb[b][c][n] (bf16) = sum_o Pb[c][o]*Ao[b][n][o]+pb[c]
// grid (8 b, 36 ntile, 2 ctile), 128 thr (2 waves).
// ---------------------------------------------------------------------------
__global__ __launch_bounds__(128) void proj_mfma_k(
    const unsigned short* __restrict__ Pb, const unsigned short* __restrict__ Ao,
    const float* __restrict__ pb, unsigned short* __restrict__ projb,
    float* __restrict__ psum, float* __restrict__ psq)
{
    __shared__ unsigned short sE[2][64 * 72];
    const int tid = threadIdx.x;
    const int wave = tid >> 6;
    const int lane = tid & 63;
    const int quad = lane >> 4;
    const int l15  = lane & 15;
    const int b  = blockIdx.x;
    const int nb = blockIdx.y * 64;
    const int mb = blockIdx.z * 128 + wave * 64;
    const int part = b * NTILES + blockIdx.y;   // 0..287

    const unsigned short* Ab = Pb + (size_t)(mb + l15) * CCH + quad * 8;
    const unsigned short* Bb = Ao + ((size_t)(b * NN + nb + l15)) * CCH + quad * 8;

    f32x4 C[4][4] = {};
    bf16x8 aA[2][4], bB[2][4];
    #pragma unroll
    for (int i = 0; i < 4; ++i) aA[0][i] = *(const bf16x8*)(Ab + (size_t)(16*i) * CCH);
    #pragma unroll
    for (int j = 0; j < 4; ++j) bB[0][j] = *(const bf16x8*)(Bb + (size_t)(16*j) * CCH);

    #pragma unroll
    for (int kk = 0; kk < 8; ++kk) {
        const int cur = kk & 1;
        if (kk < 7) {
            const int k1 = (kk + 1) * 32;
            #pragma unroll
            for (int i = 0; i < 4; ++i) aA[cur^1][i] = *(const bf16x8*)(Ab + (size_t)(16*i) * CCH + k1);
            #pragma unroll
            for (int j = 0; j < 4; ++j) bB[cur^1][j] = *(const bf16x8*)(Bb + (size_t)(16*j) * CCH + k1);
        }
        #pragma unroll
        for (int i = 0; i < 4; ++i)
            #pragma unroll
            for (int j = 0; j < 4; ++j)
                C[i][j] = MFMA32(aA[cur][i], bB[cur][j], C[i][j]);
    }

    unsigned short* sEw = &sE[wave][0];
    #pragma unroll
    for (int i = 0; i < 4; ++i) {
        #pragma unroll
        for (int r = 0; r < 4; ++r) {
            const int ch = mb + 16*i + quad*4 + r;
            const float bias = pb[ch];
            float v0 = C[i][0][r] + bias, v1 = C[i][1][r] + bias;
            float v2 = C[i][2][r] + bias, v3 = C[i][3][r] + bias;
            C[i][0][r] = v0; C[i][1][r] = v1; C[i][2][r] = v2; C[i][3][r] = v3;
            float rs = (v0 + v1) + (v2 + v3);
            float rq = (v0*v0 + v1*v1) + (v2*v2 + v3*v3);
            rs += __shfl_xor(rs, 1); rq += __shfl_xor(rq, 1);
            rs += __shfl_xor(rs, 2); rq += __shfl_xor(rq, 2);
            rs += __shfl_xor(rs, 4); rq += __shfl_xor(rq, 4);
            rs += __shfl_xor(rs, 8); rq += __shfl_xor(rq, 8);
            if (l15 == 0) {
                psum[(size_t)ch * NPART + part] = rs;
                psq [(size_t)ch * NPART + part] = rq;
            }
        }
    }

    // bf16 output via LDS transpose: rows = c_local, cols = n
    #pragma unroll
    for (int i = 0; i < 4; ++i)
        #pragma unroll
        for (int j = 0; j < 4; ++j) {
            unsigned p01 = bfpair(C[i][j][0], C[i][j][1]);
            unsigned p23 = bfpair(C[i][j][2], C[i][j][3]);
            unsigned short* p = sEw + (16*i + quad*4) * 72 + 16*j + l15;
            p[0]   = (unsigned short)p01;
            p[72]  = (unsigned short)(p01 >> 16);
            p[144] = (unsigned short)p23;
            p[216] = (unsigned short)(p23 >> 16);
        }
    #pragma unroll
    for (int it = 0; it < 8; ++it) {
        int flat = lane + 64 * it;
        int row = flat >> 3;                // c local
        int n8  = (flat & 7) * 8;
        uint4 v = *(const uint4*)(sEw + row * 72 + n8);
        *(uint4*)(projb + ((size_t)(b * CCH + mb + row)) * NN + nb + n8) = v;
    }
}

// ---------------------------------------------------------------------------
// K4: fused BN finalize + apply. grid (8 b, 256 c), 256 thr.
// out = scale[c]*projb + shift[c] + xb   (projb, xb bf16; out fp32)
// ---------------------------------------------------------------------------
__global__ __launch_bounds__(256) void bn_apply_k(
    const unsigned short* __restrict__ projb, const unsigned short* __restrict__ xb,
    const float* __restrict__ psum, const float* __restrict__ psq,
    const float* __restrict__ gamma, const float* __restrict__ beta,
    float* __restrict__ out)
{
    const int tid = threadIdx.x;
    const int b = blockIdx.x;
    const int c = blockIdx.y;

    float s = 0.f, q = 0.f;
    for (int k = tid; k < NPART; k += 256) {
        s += psum[(size_t)c * NPART + k];
        q += psq [(size_t)c * NPART + k];
    }
    __shared__ float rs[256], rq[256];
    rs[tid] = s; rq[tid] = q;
    __syncthreads();
    for (int off = 128; off > 0; off >>= 1) {
        if (tid < off) { rs[tid] += rs[tid + off]; rq[tid] += rq[tid + off]; }
        __syncthreads();
    }
    const float inv_n = 1.0f / (float)(BB * NN);
    float mean = rs[0] * inv_n;
    float var  = rq[0] * inv_n - mean * mean;
    float scv = gamma[c] * rsqrtf(var + BN_EPS);
    float shv = beta[c] - mean * scv;

    #pragma unroll
    for (int it = 0; it < 2; ++it) {
        int chunk = tid + 256 * it;
        if (chunk < 288) {
            size_t base = ((size_t)(b * CCH + c)) * NN + chunk * 8;
            uint4 pv = *(const uint4*)(projb + base);
            uint4 xv = *(const uint4*)(xb + base);
            const unsigned short* pp = (const unsigned short*)&pv;
            const unsigned short* xx = (const unsigned short*)&xv;
            float4 r0, r1;
            r0.x = scv * bf2f(pp[0]) + shv + bf2f(xx[0]);
            r0.y = scv * bf2f(pp[1]) + shv + bf2f(xx[1]);
            r0.z = scv * bf2f(pp[2]) + shv + bf2f(xx[2]);
            r0.w = scv * bf2f(pp[3]) + shv + bf2f(xx[3]);
            r1.x = scv * bf2f(pp[4]) + shv + bf2f(xx[4]);
            r1.y = scv * bf2f(pp[5]) + shv + bf2f(xx[5]);
            r1.z = scv * bf2f(pp[6]) + shv + bf2f(xx[6]);
            r1.w = scv * bf2f(pp[7]) + shv + bf2f(xx[7]);
            *(float4*)(out + base) = r0;
            *(float4*)(out + base + 4) = r1;
        }
    }
}

extern "C" void kernel_launch(void* const* d_in, const int* in_sizes, int n_in,
                              void* d_out, int out_size, void* d_ws, size_t ws_size,
                              hipStream_t stream)
{
    const float* x     = (const float*)d_in[0];
    const float* qw    = (const float*)d_in[1];
    const float* kw    = (const float*)d_in[2];
    const float* vw    = (const float*)d_in[3];
    const float* pw    = (const float*)d_in[4];
    const float* pb    = (const float*)d_in[5];
    const float* gamma = (const float*)d_in[6];
    const float* beta  = (const float*)d_in[7];
    float* out = (float*)d_out;

    char* ws = (char*)d_ws;
    // Ao overlays xT (dead after K1); projb overlays Qt (dead after K2).
    unsigned short* xT = (unsigned short*)ws;                       //  9,437,184
    unsigned short* Ao = (unsigned short*)ws;                       //  overlay
    unsigned short* Wb = (unsigned short*)(ws + 9437184);           //    196,608
    unsigned short* Pb = (unsigned short*)(ws + 9633792);           //    131,072
    unsigned short* Qt = (unsigned short*)(ws + 9764864);           //  9,437,184
    unsigned short* Kt = (unsigned short*)(ws + 19202048);          //  2,359,296
    unsigned short* Vn = (unsigned short*)(ws + 21561344);          //  2,359,296
    unsigned short* projb = (unsigned short*)(ws + 9764864);        //  overlay (9.4 MB)
    float* psum  = (float*)(ws + 28639232);                         //    294,912
    float* psq   = (float*)(ws + 28934144);                         //    294,912
    unsigned short* xb = (unsigned short*)(ws + 29229056);          //  4,718,592

    prep_k<<<1792, 256, 0, stream>>>(x, qw, kw, vw, pw, xT, xb, Wb, Pb);

    dim3 g1(BB, NN / 64, 3);
    qkv_mfma_k<<<g1, 128, 0, stream>>>(Wb, xT, Qt, Kt, Vn);

    dim3 g2(NN / 64, NH, BB);   // b slowest: same-b blocks dispatch together
    attn_k<<<g2, 64, 0, stream>>>(Qt, Kt, Vn, Ao);

    dim3 g3(BB, NN / 64, 2);
    proj_mfma_k<<<g3, 128, 0, stream>>>(Pb, Ao, pb, projb, psum, psq);

    dim3 g4(BB, CCH);
    bn_apply_k<<<g4, 256, 0, stream>>>(projb, xb, psum, psq, gamma, beta, out);
}

// Round 9
// 190.039 us; speedup vs baseline: 1.3400x; 1.3400x over previous
//
#include <hip/hip_runtime.h>
#include <hip/hip_bf16.h>
#include <math.h>

#define BB 8
#define CCH 256          // channels
#define NN 2304          // H*W
#define NH 4
#define HDIM 64
#define QKV_ROWS 384
#define BN_EPS 1e-5f
#define NTILES 36        // NN / 64
#define NPART 288        // BB * 36 proj blocks contributing per channel
// scale folded into q weights: 1/sqrt(64) * log2(e)  -> attention uses exp2
#define SLOG2E 0.18033688011112042f

typedef short bf16x8 __attribute__((ext_vector_type(8)));
typedef short bf16x4 __attribute__((ext_vector_type(4)));
typedef float f32x4 __attribute__((ext_vector_type(4)));

#if __has_builtin(__builtin_amdgcn_exp2f)
#define EXP2(x) __builtin_amdgcn_exp2f(x)
#else
#define EXP2(x) __expf((x) * 0.6931471805599453f)
#endif

#define MFMA32(a, b, c) __builtin_amdgcn_mfma_f32_16x16x32_bf16(a, b, c, 0, 0, 0)

__device__ __forceinline__ unsigned bfpair(float a, float b) {
    __hip_bfloat162 h = __float22bfloat162_rn(make_float2(a, b));
    return *(unsigned*)&h;
}
__device__ __forceinline__ unsigned short f2bf(float f) {
    unsigned u = __float_as_uint(f);
    u = (u + 0x7FFFu + ((u >> 16) & 1u)) >> 16;
    return (unsigned short)u;
}
__device__ __forceinline__ float bf2f(unsigned short s) {
    return __uint_as_float((unsigned)s << 16);
}

// ---------------------------------------------------------------------------
// K0: prep — x-transpose/convert + weight convert. (round-25: xb dropped —
// bn_apply reads x fp32 directly; saves a 9.4MB store pass and improves the
// residual's accuracy.)
// ---------------------------------------------------------------------------
__global__ __launch_bounds__(256) void prep_k(
    const float* __restrict__ x,
    const float* __restrict__ qw, const float* __restrict__ kw,
    const float* __restrict__ vw, const float* __restrict__ pw,
    unsigned short* __restrict__ xT,
    unsigned short* __restrict__ Wb, unsigned short* __restrict__ Pb)
{
    const int bid = blockIdx.x;
    const int tid = threadIdx.x;
    if (bid < 1152) {
        __shared__ float sX[64][65];
        const int b  = bid / 144;
        const int rem = bid - b * 144;
        const int nb = (rem >> 2) * 64;
        const int cb = (rem & 3) * 64;

        #pragma unroll
        for (int u = 0; u < 4; ++u) {
            int c  = (tid >> 4) + 16 * u;
            int n4 = (tid & 15) * 4;
            float4 v = *(const float4*)(x + ((size_t)(b * CCH + cb + c)) * NN + nb + n4);
            sX[c][n4+0] = v.x; sX[c][n4+1] = v.y; sX[c][n4+2] = v.z; sX[c][n4+3] = v.w;
        }
        __syncthreads();

        // xT[b][n][c] (transposed)
        const int n  = tid >> 2;
        const int cg = (tid & 3) * 16;
        unsigned vals[8];
        #pragma unroll
        for (int p = 0; p < 8; ++p)
            vals[p] = bfpair(sX[cg + 2*p][n], sX[cg + 2*p + 1][n]);
        unsigned short* dst = xT + ((size_t)(b * NN + nb + n)) * CCH + cb + cg;
        *(uint4*)dst = make_uint4(vals[0], vals[1], vals[2], vals[3]);
        *(uint4*)(dst + 8) = make_uint4(vals[4], vals[5], vals[6], vals[7]);
    } else {
        int idx = (bid - 1152) * 256 + tid;
        if (idx < 98304) {
            int o = idx >> 8, c = idx & 255;
            float v;
            if (o < 256)      v = qw[(size_t)o * CCH + c] * SLOG2E;
            else if (o < 320) v = kw[(size_t)(o - 256) * CCH + c];
            else              v = vw[(size_t)(o - 320) * CCH + c];
            Wb[idx] = f2bf(v);
        } else {
            int j = idx - 98304;
            if (j < 65536) Pb[j] = f2bf(pw[j]);
        }
    }
}

// ---------------------------------------------------------------------------
// K1: qkv MFMA GEMM, K-loop software-pipelined (round-11/13 verified 64x64).
// grid (8 b, 36 ntile, 3 otile), 128 thr (2 waves).
//   Qt[b][n][256] (q pre-scaled), Kt[b][n][64], Vn[b][64][n], all bf16.
// ---------------------------------------------------------------------------
__global__ __launch_bounds__(128) void qkv_mfma_k(
    const unsigned short* __restrict__ Wb, const unsigned short* __restrict__ xT,
    unsigned short* __restrict__ Qt, unsigned short* __restrict__ Kt,
    unsigned short* __restrict__ Vn)
{
    __shared__ unsigned short sE[2][64 * 72];
    const int tid = threadIdx.x;
    const int wave = tid >> 6;
    const int lane = tid & 63;
    const int quad = lane >> 4;
    const int l15  = lane & 15;
    const int b  = blockIdx.x;
    const int nb = blockIdx.y * 64;
    const int mb = blockIdx.z * 128 + wave * 64;

    const unsigned short* Ab = Wb + (size_t)(mb + l15) * CCH + quad * 8;
    const unsigned short* Bb = xT + ((size_t)(b * NN + nb + l15)) * CCH + quad * 8;

    f32x4 C[4][4] = {};
    bf16x8 aA[2][4], bB[2][4];
    #pragma unroll
    for (int i = 0; i < 4; ++i) aA[0][i] = *(const bf16x8*)(Ab + (size_t)(16*i) * CCH);
    #pragma unroll
    for (int j = 0; j < 4; ++j) bB[0][j] = *(const bf16x8*)(Bb + (size_t)(16*j) * CCH);

    #pragma unroll
    for (int kk = 0; kk < 8; ++kk) {
        const int cur = kk & 1;
        if (kk < 7) {
            const int k1 = (kk + 1) * 32;
            #pragma unroll
            for (int i = 0; i < 4; ++i) aA[cur^1][i] = *(const bf16x8*)(Ab + (size_t)(16*i) * CCH + k1);
            #pragma unroll
            for (int j = 0; j < 4; ++j) bB[cur^1][j] = *(const bf16x8*)(Bb + (size_t)(16*j) * CCH + k1);
        }
        #pragma unroll
        for (int i = 0; i < 4; ++i)
            #pragma unroll
            for (int j = 0; j < 4; ++j)
                C[i][j] = MFMA32(aA[cur][i], bB[cur][j], C[i][j]);
    }

    unsigned short* sEw = &sE[wave][0];
    if (mb < 320) {
        // Q or K: transpose to [n][o] rows
        #pragma unroll
        for (int i = 0; i < 4; ++i)
            #pragma unroll
            for (int j = 0; j < 4; ++j) {
                unsigned p01 = bfpair(C[i][j][0], C[i][j][1]);
                unsigned p23 = bfpair(C[i][j][2], C[i][j][3]);
                unsigned short* p = sEw + (16*j + l15) * 72 + 16*i + quad*4;
                *(unsigned*)p = p01;
                *(unsigned*)(p + 2) = p23;
            }
        if (mb < 256) {
            #pragma unroll
            for (int it = 0; it < 8; ++it) {
                int flat = lane + 64 * it;
                int row = flat >> 3;
                int o8  = (flat & 7) * 8;
                uint4 v = *(const uint4*)(sEw + row * 72 + o8);
                *(uint4*)(Qt + ((size_t)(b * NN + nb + row)) * CCH + mb + o8) = v;
            }
        } else {
            #pragma unroll
            for (int it = 0; it < 8; ++it) {
                int flat = lane + 64 * it;
                int row = flat >> 3;
                int o8  = (flat & 7) * 8;
                uint4 v = *(const uint4*)(sEw + row * 72 + o8);
                *(uint4*)(Kt + ((size_t)(b * NN + nb + row)) * 64 + o8) = v;
            }
        }
    } else {
        // V: [d][n] rows
        #pragma unroll
        for (int i = 0; i < 4; ++i)
            #pragma unroll
            for (int j = 0; j < 4; ++j) {
                unsigned p01 = bfpair(C[i][j][0], C[i][j][1]);
                unsigned p23 = bfpair(C[i][j][2], C[i][j][3]);
                unsigned short* p = sEw + (16*i + quad*4) * 72 + 16*j + l15;
                p[0]   = (unsigned short)p01;
                p[72]  = (unsigned short)(p01 >> 16);
                p[144] = (unsigned short)p23;
                p[216] = (unsigned short)(p23 >> 16);
            }
        #pragma unroll
        for (int it = 0; it < 8; ++it) {
            int flat = lane + 64 * it;
            int row = flat >> 3;
            int n8  = (flat & 7) * 8;
            uint4 v = *(const uint4*)(sEw + row * 72 + n8);
            *(uint4*)(Vn + ((size_t)(b * 64 + (mb - 320) + row)) * NN + nb + n8) = v;
        }
    }
}

// ---------------------------------------------------------------------------
// K2: MFMA attention — round-25: r23 structure (verified 69.5 us) + wave-
// parity PHASE STAGGER. Evidence r17-r24: per-CU busy times (MFMA 23.6,
// VALU ~25, LDS ~26 us) and measured walls 70-75 us => pipes barely overlap
// in ANY config; barriered waves are phase-locked (all in the same
// MFMA-vs-VALU burst). r24 (no barriers, 1-wave blocks) failed on TLP: 2
// waves/CU can't hide even in-wave latency. Stagger instead: within each
// barrier interval, EVEN waves run [PV(s-1) -> QK(s) -> exp2(s)], ODD waves
// run [QK(s) -> exp2(s) -> PV(s-1)] -> at any instant half the waves are in
// a VALU burst while half are in MFMA. Numerics bit-identical (same
// clusters, same per-accumulator order); V[s-1] tribuf lifetime spans the
// whole interval so the late PV read is safe. Branch is wave-uniform
// (scalar s_cbranch). r10/r16/r22 lesson: staging geometry untouched.
// ---------------------------------------------------------------------------
// element offsets into sKV (unsigned short units):
//   K slots: 0, 4096   (2 x 64x64)
//   V slots: 8192, 12288, 16384   (3 x 64x64)
#define PV_CLUSTER(VPRV, BPP)                                                    \
    {                                                                            \
        __builtin_amdgcn_s_setprio(1);                                           \
        _Pragma("unroll")                                                        \
        for (int jd_ = 0; jd_ < 4; ++jd_) {                                      \
            _Pragma("unroll")                                                    \
            for (int kt2_ = 0; kt2_ < 2; ++kt2_) {                               \
                const int row_ = 16 * jd_ + l15;                                 \
                const int ch_ = ((4 * kt2_ + quad) ^ (row_ & 7)) * 8;            \
                bf16x8 aV_ = *(const bf16x8*)(sKV + (VPRV) + row_ * 64 + ch_);   \
                O[jd_][0] = MFMA32(aV_, BPP[kt2_][0], O[jd_][0]);                \
                O[jd_][1] = MFMA32(aV_, BPP[kt2_][1], O[jd_][1]);                \
            }                                                                    \
        }                                                                        \
        dacc[0] = MFMA32(vone8, BPP[0][0], dacc[0]);                             \
        dacc[1] = MFMA32(vone8, BPP[0][1], dacc[1]);                             \
        dacc[0] = MFMA32(vone8, BPP[1][0], dacc[0]);                             \
        dacc[1] = MFMA32(vone8, BPP[1][1], dacc[1]);                             \
        __builtin_amdgcn_s_setprio(0);                                           \
    }

#define QK_CLUSTER(KCUR, CARR)                                                   \
    {                                                                            \
        __builtin_amdgcn_s_setprio(1);                                           \
        _Pragma("unroll")                                                        \
        for (int s_ = 0; s_ < 2; ++s_) {                                         \
            _Pragma("unroll")                                                    \
            for (int kt_ = 0; kt_ < 4; ++kt_) {                                  \
                const int row_ = 16 * kt_ + l15;                                 \
                const int ch_ = ((s_ * 4 + quad) ^ (row_ & 7)) * 8;              \
                bf16x8 aK_ = *(const bf16x8*)(sKV + (KCUR) + row_ * 64 + ch_);   \
                CARR[kt_][0] = MFMA32(aK_, bQ[0][s_], CARR[kt_][0]);             \
                CARR[kt_][1] = MFMA32(aK_, bQ[1][s_], CARR[kt_][1]);             \
            }                                                                    \
        }                                                                        \
        __builtin_amdgcn_s_setprio(0);                                           \
    }

#define EXP_CLUSTER(CARR, BPN)                                                   \
    {                                                                            \
        _Pragma("unroll")                                                        \
        for (int kt2_ = 0; kt2_ < 2; ++kt2_) {                                   \
            _Pragma("unroll")                                                    \
            for (int qt_ = 0; qt_ < 2; ++qt_) {                                  \
                union { unsigned u[4]; bf16x8 v; } xp_;                          \
                const f32x4 c0_ = CARR[2 * kt2_][qt_];                           \
                const f32x4 c1_ = CARR[2 * kt2_ + 1][qt_];                       \
                xp_.u[0] = bfpair(EXP2(c0_[0]), EXP2(c0_[1]));                   \
                xp_.u[1] = bfpair(EXP2(c0_[2]), EXP2(c0_[3]));                   \
                xp_.u[2] = bfpair(EXP2(c1_[0]), EXP2(c1_[1]));                   \
                xp_.u[3] = bfpair(EXP2(c1_[2]), EXP2(c1_[3]));                   \
                BPN[kt2_][qt_] = xp_.v;                                          \
            }                                                                    \
        }                                                                        \
    }

#define ATT_STEP(STEPN, KCUR, KNXT, VPRV, VNXT, BPP, BPN, DOPV)                  \
    {                                                                            \
        __syncthreads();                                                         \
        if ((STEPN) + 1 < NTILES) {                                              \
            *(bf16x8*)(sKV + (KNXT) + kr0 * 64 + kwc)        = pf[0];            \
            *(bf16x8*)(sKV + (KNXT) + (kr0 + 32) * 64 + kwc) = pf[1];            \
            *(bf16x8*)(sKV + (VNXT) + r0 * 64 + vwc)         = pf[2];            \
            *(bf16x8*)(sKV + (VNXT) + (r0 + 32) * 64 + vwc)  = pf[3];            \
        }                                                                        \
        if ((STEPN) + 2 < NTILES) {                                              \
            const int keys0_ = ((STEPN) + 2) * 64;                               \
            pf[0] = *(const bf16x8*)(Kb + (size_t)keys0_ * 64);                  \
            pf[1] = *(const bf16x8*)(Kb + (size_t)(keys0_ + 32) * 64);           \
            pf[2] = *(const bf16x8*)(Vb + keys0_);                               \
            pf[3] = *(const bf16x8*)(Vb + (size_t)32 * NN + keys0_);             \
        }                                                                        \
        f32x4 C_[4][2] = {};                                                     \
        if (evenw) {                                                             \
            if (DOPV) PV_CLUSTER(VPRV, BPP);                                     \
            QK_CLUSTER(KCUR, C_);                                                \
            EXP_CLUSTER(C_, BPN);                                                \
        } else {                                                                 \
            QK_CLUSTER(KCUR, C_);                                                \
            EXP_CLUSTER(C_, BPN);                                                \
            if (DOPV) PV_CLUSTER(VPRV, BPP);                                     \
        }                                                                        \
    }

#define ROTV(x) x = ((x) == 16384) ? 8192 : (x) + 4096

__global__ __launch_bounds__(256, 3) void attn_k(
    const unsigned short* __restrict__ Qt,  // [B][N][256]
    const unsigned short* __restrict__ Kt,  // [B][N][64]
    const unsigned short* __restrict__ Vn,  // [B][64][N]
    unsigned short* __restrict__ Ao)        // [B][N][256]
{
    // K dbuf (2x4096 elems) + V tribuf (3x4096 elems) = 20480 shorts = 40 KB
    __shared__ __align__(16) unsigned short sKV[20480];

    const int tid   = threadIdx.x;
    const int wave  = tid >> 6;      // qslot 0..3
    const int lane  = tid & 63;
    const int quad  = lane >> 4;
    const int l15   = lane & 15;
    const int qoff  = wave * 32;
    const bool evenw = (wave & 1) == 0;
    const int b     = blockIdx.x;
    const int nb    = blockIdx.y * 128;
    const int head  = blockIdx.z;

    const bf16x8 vone8 = {(short)0x3F80, (short)0x3F80, (short)0x3F80, (short)0x3F80,
                          (short)0x3F80, (short)0x3F80, (short)0x3F80, (short)0x3F80};

    // Q fragments (B-operand for S^T): B[n=query][k=d=quad*8+j], 2 q-tiles
    bf16x8 bQ[2][2];
    const unsigned short* QtB = Qt + ((size_t)(b * NN + nb + qoff + l15)) * CCH + head * 64 + quad * 8;
    #pragma unroll
    for (int qt = 0; qt < 2; ++qt)
        #pragma unroll
        for (int s = 0; s < 2; ++s)
            bQ[qt][s] = *(const bf16x8*)(QtB + (size_t)(16*qt) * CCH + s * 32);

    // staging geometry: 256 thr, 2 rows per tile each (rows r0, r0+32)
    const int r0  = tid >> 3;        // 0..31
    const int c8  = (tid & 7) * 8;   // global (unswizzled) column
    // sigma(row): key -> LDS row permutation for K tiles (bit-shuffle
    // b0b1,b3b4,b2,b5 -> row b0..b5) so S^T output tiles land with keys
    // already in MFMA32 B-fragment order (k = quad*8+j) -> lane-local P pack.
    const int kr0 = (r0 & 3) | (((r0 >> 3) & 3) << 2) | (((r0 >> 2) & 1) << 4);
    const int kwc = ((tid & 7) ^ (kr0 & 7)) * 8;   // K write col (both rows)
    const int vwc = ((tid & 7) ^ (r0 & 7)) * 8;    // V write col (both rows)

    const unsigned short* Kb = Kt + ((size_t)(b * NN + r0)) * 64 + c8;
    const unsigned short* Vb = Vn + ((size_t)(b * 64 + r0)) * NN + c8;

    bf16x8 pf[4];
    // step 0 load
    pf[0] = *(const bf16x8*)(Kb);
    pf[1] = *(const bf16x8*)(Kb + (size_t)32 * 64);
    pf[2] = *(const bf16x8*)(Vb);
    pf[3] = *(const bf16x8*)(Vb + (size_t)32 * NN);
    // write step 0 -> K slot0 (@0), V slot0 (@8192)
    *(bf16x8*)(sKV + kr0 * 64 + kwc)               = pf[0];
    *(bf16x8*)(sKV + (kr0 + 32) * 64 + kwc)        = pf[1];
    *(bf16x8*)(sKV + 8192 + r0 * 64 + vwc)         = pf[2];
    *(bf16x8*)(sKV + 8192 + (r0 + 32) * 64 + vwc)  = pf[3];
    // prefetch step 1
    pf[0] = *(const bf16x8*)(Kb + (size_t)64 * 64);
    pf[1] = *(const bf16x8*)(Kb + (size_t)96 * 64);
    pf[2] = *(const bf16x8*)(Vb + 64);
    pf[3] = *(const bf16x8*)(Vb + (size_t)32 * NN + 64);

    f32x4 O[4][2] = {};          // O^T[d-tile jd][q-tile qt]
    f32x4 dacc[2] = {};          // softmax denominators via ones-MFMA
    bf16x8 bPe[2][2], bPo[2][2]; // ping-pong P fragments (even/odd producer)

    // step 0: no deferred PV; stage step1 -> K slot1 (@4096), V slot1 (@12288)
    ATT_STEP(0, 0, 4096, 0 /*unused*/, 12288, bPo /*unused*/, bPe, 0);

    // V-slot rotation state: at step s, VPRV = slot((s-1)%3), VNXT = slot((s+1)%3)
    int vPrv = 8192;    // for step 1: V[0] @ slot0
    int vNxt = 16384;   // for step 1: V[2] -> slot2
    // pairs covering steps 1..34 (17 pairs); odd step uses K slot1, even slot0
    for (int sp = 1; sp < 35; sp += 2) {
        ATT_STEP(sp,     4096, 0,    vPrv, vNxt, bPe, bPo, 1);
        ROTV(vPrv); ROTV(vNxt);
        ATT_STEP(sp + 1, 0,    4096, vPrv, vNxt, bPo, bPe, 1);
        ROTV(vPrv); ROTV(vNxt);
    }
    // step 35 (odd): PV[34] from bPe, produce bPo; no staging/prefetch
    ATT_STEP(35, 4096, 0, vPrv, vNxt, bPe, bPo, 1);
    ROTV(vPrv);   // now = slot(35%3) = V[35]

    // epilogue: deferred PV + denominator for step 35
    PV_CLUSTER(vPrv, bPo);

    __syncthreads();   // all K/V reads done before sT overlay

    // normalize + transpose to [query][d] rows via LDS
    float rinv[2];
    rinv[0] = 1.0f / dacc[0][0];
    rinv[1] = 1.0f / dacc[1][0];
    unsigned short* sT = (unsigned short*)sKV;   // [128 n][72]
    #pragma unroll
    for (int qt = 0; qt < 2; ++qt)
        #pragma unroll
        for (int jd = 0; jd < 4; ++jd) {
            unsigned lo = bfpair(O[jd][qt][0] * rinv[qt], O[jd][qt][1] * rinv[qt]);
            unsigned hi = bfpair(O[jd][qt][2] * rinv[qt], O[jd][qt][3] * rinv[qt]);
            *(uint2*)(sT + (qoff + 16*qt + l15) * 72 + 16*jd + quad*4) = make_uint2(lo, hi);
        }
    __syncthreads();

    // coalesced writeout: 128 rows x 64 channels = 1024 uint4 chunks
    #pragma unroll
    for (int it = 0; it < 4; ++it) {
        int flat = tid + 256 * it;          // 0..1023
        int row  = flat >> 3;               // 0..127
        int cc8  = (flat & 7) * 8;
        uint4 v = *(const uint4*)(sT + row * 72 + cc8);
        *(uint4*)(Ao + ((size_t)(b * NN + nb + row)) * CCH + head * 64 + cc8) = v;
    }
}

// ---------------------------------------------------------------------------
// K3: proj MFMA GEMM (64x64 pipelined) + per-block BN partials.
// projb[b][c][n] (bf16) = sum_o Pb[c][o]*Ao[b][n][o]+pb[c]
// grid (8 b, 36 ntile, 2 ctile), 128 thr (2 waves).
// ---------------------------------------------------------------------------
__global__ __launch_bounds__(128) void proj_mfma_k(
    const unsigned short* __restrict__ Pb, const unsigned short* __restrict__ Ao,
    const float* __restrict__ pb, unsigned short* __restrict__ projb,
    float* __restrict__ psum, float* __restrict__ psq)
{
    __shared__ unsigned short sE[2][64 * 72];
    const int tid = threadIdx.x;
    const int wave = tid >> 6;
    const int lane = tid & 63;
    const int quad = lane >> 4;
    const int l15  = lane & 15;
    const int b  = blockIdx.x;
    const int nb = blockIdx.y * 64;
    const int mb = blockIdx.z * 128 + wave * 64;
    const int part = b * NTILES + blockIdx.y;   // 0..287

    const unsigned short* Ab = Pb + (size_t)(mb + l15) * CCH + quad * 8;
    const unsigned short* Bb = Ao + ((size_t)(b * NN + nb + l15)) * CCH + quad * 8;

    f32x4 C[4][4] = {};
    bf16x8 aA[2][4], bB[2][4];
    #pragma unroll
    for (int i = 0; i < 4; ++i) aA[0][i] = *(const bf16x8*)(Ab + (size_t)(16*i) * CCH);
    #pragma unroll
    for (int j = 0; j < 4; ++j) bB[0][j] = *(const bf16x8*)(Bb + (size_t)(16*j) * CCH);

    #pragma unroll
    for (int kk = 0; kk < 8; ++kk) {
        const int cur = kk & 1;
        if (kk < 7) {
            const int k1 = (kk + 1) * 32;
            #pragma unroll
            for (int i = 0; i < 4; ++i) aA[cur^1][i] = *(const bf16x8*)(Ab + (size_t)(16*i) * CCH + k1);
            #pragma unroll
            for (int j = 0; j < 4; ++j) bB[cur^1][j] = *(const bf16x8*)(Bb + (size_t)(16*j) * CCH + k1);
        }
        #pragma unroll
        for (int i = 0; i < 4; ++i)
            #pragma unroll
            for (int j = 0; j < 4; ++j)
                C[i][j] = MFMA32(aA[cur][i], bB[cur][j], C[i][j]);
    }

    unsigned short* sEw = &sE[wave][0];
    #pragma unroll
    for (int i = 0; i < 4; ++i) {
        #pragma unroll
        for (int r = 0; r < 4; ++r) {
            const int ch = mb + 16*i + quad*4 + r;
            const float bias = pb[ch];
            float v0 = C[i][0][r] + bias, v1 = C[i][1][r] + bias;
            float v2 = C[i][2][r] + bias, v3 = C[i][3][r] + bias;
            C[i][0][r] = v0; C[i][1][r] = v1; C[i][2][r] = v2; C[i][3][r] = v3;
            float rs = (v0 + v1) + (v2 + v3);
            float rq = (v0*v0 + v1*v1) + (v2*v2 + v3*v3);
            rs += __shfl_xor(rs, 1); rq += __shfl_xor(rq, 1);
            rs += __shfl_xor(rs, 2); rq += __shfl_xor(rq, 2);
            rs += __shfl_xor(rs, 4); rq += __shfl_xor(rq, 4);
            rs += __shfl_xor(rs, 8); rq += __shfl_xor(rq, 8);
            if (l15 == 0) {
                psum[(size_t)ch * NPART + part] = rs;
                psq [(size_t)ch * NPART + part] = rq;
            }
        }
    }

    // bf16 output via LDS transpose: rows = c_local, cols = n
    #pragma unroll
    for (int i = 0; i < 4; ++i)
        #pragma unroll
        for (int j = 0; j < 4; ++j) {
            unsigned p01 = bfpair(C[i][j][0], C[i][j][1]);
            unsigned p23 = bfpair(C[i][j][2], C[i][j][3]);
            unsigned short* p = sEw + (16*i + quad*4) * 72 + 16*j + l15;
            p[0]   = (unsigned short)p01;
            p[72]  = (unsigned short)(p01 >> 16);
            p[144] = (unsigned short)p23;
            p[216] = (unsigned short)(p23 >> 16);
        }
    #pragma unroll
    for (int it = 0; it < 8; ++it) {
        int flat = lane + 64 * it;
        int row = flat >> 3;                // c local
        int n8  = (flat & 7) * 8;
        uint4 v = *(const uint4*)(sEw + row * 72 + n8);
        *(uint4*)(projb + ((size_t)(b * CCH + mb + row)) * NN + nb + n8) = v;
    }
}

// ---------------------------------------------------------------------------
// K4: fused BN finalize + apply. grid (8 b, 256 c), 256 thr.
// out = scale[c]*projb + shift[c] + x   (projb bf16, x fp32; out fp32)
// round-25: stats via wave shuffle (no 8-round LDS tree); residual read
// directly from x in fp32 (xb eliminated).
// ---------------------------------------------------------------------------
__global__ __launch_bounds__(256) void bn_apply_k(
    const unsigned short* __restrict__ projb, const float* __restrict__ x,
    const float* __restrict__ psum, const float* __restrict__ psq,
    const float* __restrict__ gamma, const float* __restrict__ beta,
    float* __restrict__ out)
{
    const int tid = threadIdx.x;
    const int b = blockIdx.x;
    const int c = blockIdx.y;

    float s = 0.f, q = 0.f;
    for (int k = tid; k < NPART; k += 256) {
        s += psum[(size_t)c * NPART + k];
        q += psq [(size_t)c * NPART + k];
    }
    // wave-level butterfly, then 4 wave-partials summed by every thread
    #pragma unroll
    for (int off = 32; off > 0; off >>= 1) {
        s += __shfl_xor(s, off);
        q += __shfl_xor(q, off);
    }
    __shared__ float ws[8];
    if ((tid & 63) == 0) { ws[tid >> 6] = s; ws[4 + (tid >> 6)] = q; }
    __syncthreads();
    const float S = (ws[0] + ws[1]) + (ws[2] + ws[3]);
    const float Q = (ws[4] + ws[5]) + (ws[6] + ws[7]);

    const float inv_n = 1.0f / (float)(BB * NN);
    float mean = S * inv_n;
    float var  = Q * inv_n - mean * mean;
    float scv = gamma[c] * rsqrtf(var + BN_EPS);
    float shv = beta[c] - mean * scv;

    #pragma unroll
    for (int it = 0; it < 2; ++it) {
        int chunk = tid + 256 * it;
        if (chunk < 288) {
            size_t base = ((size_t)(b * CCH + c)) * NN + chunk * 8;
            uint4 pv = *(const uint4*)(projb + base);
            float4 xv0 = *(const float4*)(x + base);
            float4 xv1 = *(const float4*)(x + base + 4);
            const unsigned short* pp = (const unsigned short*)&pv;
            float4 r0, r1;
            r0.x = scv * bf2f(pp[0]) + shv + xv0.x;
            r0.y = scv * bf2f(pp[1]) + shv + xv0.y;
            r0.z = scv * bf2f(pp[2]) + shv + xv0.z;
            r0.w = scv * bf2f(pp[3]) + shv + xv0.w;
            r1.x = scv * bf2f(pp[4]) + shv + xv1.x;
            r1.y = scv * bf2f(pp[5]) + shv + xv1.y;
            r1.z = scv * bf2f(pp[6]) + shv + xv1.z;
            r1.w = scv * bf2f(pp[7]) + shv + xv1.w;
            *(float4*)(out + base) = r0;
            *(float4*)(out + base + 4) = r1;
        }
    }
}

extern "C" void kernel_launch(void* const* d_in, const int* in_sizes, int n_in,
                              void* d_out, int out_size, void* d_ws, size_t ws_size,
                              hipStream_t stream)
{
    const float* x     = (const float*)d_in[0];
    const float* qw    = (const float*)d_in[1];
    const float* kw    = (const float*)d_in[2];
    const float* vw    = (const float*)d_in[3];
    const float* pw    = (const float*)d_in[4];
    const float* pb    = (const float*)d_in[5];
    const float* gamma = (const float*)d_in[6];
    const float* beta  = (const float*)d_in[7];
    float* out = (float*)d_out;

    char* ws = (char*)d_ws;
    // Ao overlays xT (dead after K1); projb overlays Qt (dead after K2).
    unsigned short* xT = (unsigned short*)ws;                       //  9,437,184
    unsigned short* Ao = (unsigned short*)ws;                       //  overlay
    unsigned short* Wb = (unsigned short*)(ws + 9437184);           //    196,608
    unsigned short* Pb = (unsigned short*)(ws + 9633792);           //    131,072
    unsigned short* Qt = (unsigned short*)(ws + 9764864);           //  9,437,184
    unsigned short* Kt = (unsigned short*)(ws + 19202048);          //  2,359,296
    unsigned short* Vn = (unsigned short*)(ws + 21561344);          //  2,359,296
    unsigned short* projb = (unsigned short*)(ws + 9764864);        //  overlay (9.4 MB)
    float* psum  = (float*)(ws + 28639232);                         //    294,912
    float* psq   = (float*)(ws + 28934144);                         //    294,912

    prep_k<<<1792, 256, 0, stream>>>(x, qw, kw, vw, pw, xT, Wb, Pb);

    dim3 g1(BB, NN / 64, 3);
    qkv_mfma_k<<<g1, 128, 0, stream>>>(Wb, xT, Qt, Kt, Vn);

    dim3 g2(BB, NN / 128, NH);
    attn_k<<<g2, 256, 0, stream>>>(Qt, Kt, Vn, Ao);

    dim3 g3(BB, NN / 64, 2);
    proj_mfma_k<<<g3, 128, 0, stream>>>(Pb, Ao, pb, projb, psum, psq);

    dim3 g4(BB, CCH);
    bn_apply_k<<<g4, 256, 0, stream>>>(projb, x, psum, psq, gamma, beta, out);
}

// Round 10
// 187.178 us; speedup vs baseline: 1.3605x; 1.0153x over previous
//
#include <hip/hip_runtime.h>
#include <hip/hip_bf16.h>
#include <math.h>

#define BB 8
#define CCH 256          // channels
#define NN 2304          // H*W
#define NH 4
#define HDIM 64
#define QKV_ROWS 384
#define BN_EPS 1e-5f
#define NTILES 36        // NN / 64
#define NPART 288        // BB * 36 proj blocks contributing per channel
// scale folded into q weights: 1/sqrt(64) * log2(e)  -> attention uses exp2
#define SLOG2E 0.18033688011112042f

typedef short bf16x8 __attribute__((ext_vector_type(8)));
typedef short bf16x4 __attribute__((ext_vector_type(4)));
typedef float f32x4 __attribute__((ext_vector_type(4)));

#if __has_builtin(__builtin_amdgcn_exp2f)
#define EXP2(x) __builtin_amdgcn_exp2f(x)
#else
#define EXP2(x) __expf((x) * 0.6931471805599453f)
#endif

#define MFMA32(a, b, c) __builtin_amdgcn_mfma_f32_16x16x32_bf16(a, b, c, 0, 0, 0)

__device__ __forceinline__ unsigned bfpair(float a, float b) {
    __hip_bfloat162 h = __float22bfloat162_rn(make_float2(a, b));
    return *(unsigned*)&h;
}
__device__ __forceinline__ unsigned short f2bf(float f) {
    unsigned u = __float_as_uint(f);
    u = (u + 0x7FFFu + ((u >> 16) & 1u)) >> 16;
    return (unsigned short)u;
}
__device__ __forceinline__ float bf2f(unsigned short s) {
    return __uint_as_float((unsigned)s << 16);
}

// ---------------------------------------------------------------------------
// K0: prep — x-transpose/convert + weight convert. (r25: xb dropped —
// bn_apply reads x fp32 directly; saves a 9.4MB store pass and improves the
// residual's accuracy. Verified -1.5us on the non-attn path.)
// ---------------------------------------------------------------------------
__global__ __launch_bounds__(256) void prep_k(
    const float* __restrict__ x,
    const float* __restrict__ qw, const float* __restrict__ kw,
    const float* __restrict__ vw, const float* __restrict__ pw,
    unsigned short* __restrict__ xT,
    unsigned short* __restrict__ Wb, unsigned short* __restrict__ Pb)
{
    const int bid = blockIdx.x;
    const int tid = threadIdx.x;
    if (bid < 1152) {
        __shared__ float sX[64][65];
        const int b  = bid / 144;
        const int rem = bid - b * 144;
        const int nb = (rem >> 2) * 64;
        const int cb = (rem & 3) * 64;

        #pragma unroll
        for (int u = 0; u < 4; ++u) {
            int c  = (tid >> 4) + 16 * u;
            int n4 = (tid & 15) * 4;
            float4 v = *(const float4*)(x + ((size_t)(b * CCH + cb + c)) * NN + nb + n4);
            sX[c][n4+0] = v.x; sX[c][n4+1] = v.y; sX[c][n4+2] = v.z; sX[c][n4+3] = v.w;
        }
        __syncthreads();

        // xT[b][n][c] (transposed)
        const int n  = tid >> 2;
        const int cg = (tid & 3) * 16;
        unsigned vals[8];
        #pragma unroll
        for (int p = 0; p < 8; ++p)
            vals[p] = bfpair(sX[cg + 2*p][n], sX[cg + 2*p + 1][n]);
        unsigned short* dst = xT + ((size_t)(b * NN + nb + n)) * CCH + cb + cg;
        *(uint4*)dst = make_uint4(vals[0], vals[1], vals[2], vals[3]);
        *(uint4*)(dst + 8) = make_uint4(vals[4], vals[5], vals[6], vals[7]);
    } else {
        int idx = (bid - 1152) * 256 + tid;
        if (idx < 98304) {
            int o = idx >> 8, c = idx & 255;
            float v;
            if (o < 256)      v = qw[(size_t)o * CCH + c] * SLOG2E;
            else if (o < 320) v = kw[(size_t)(o - 256) * CCH + c];
            else              v = vw[(size_t)(o - 320) * CCH + c];
            Wb[idx] = f2bf(v);
        } else {
            int j = idx - 98304;
            if (j < 65536) Pb[j] = f2bf(pw[j]);
        }
    }
}

// ---------------------------------------------------------------------------
// K1: qkv MFMA GEMM, K-loop software-pipelined (round-11/13 verified 64x64).
// grid (8 b, 36 ntile, 3 otile), 128 thr (2 waves).
//   Qt[b][n][256] (q pre-scaled), Kt[b][n][64], Vn[b][64][n], all bf16.
// ---------------------------------------------------------------------------
__global__ __launch_bounds__(128) void qkv_mfma_k(
    const unsigned short* __restrict__ Wb, const unsigned short* __restrict__ xT,
    unsigned short* __restrict__ Qt, unsigned short* __restrict__ Kt,
    unsigned short* __restrict__ Vn)
{
    __shared__ unsigned short sE[2][64 * 72];
    const int tid = threadIdx.x;
    const int wave = tid >> 6;
    const int lane = tid & 63;
    const int quad = lane >> 4;
    const int l15  = lane & 15;
    const int b  = blockIdx.x;
    const int nb = blockIdx.y * 64;
    const int mb = blockIdx.z * 128 + wave * 64;

    const unsigned short* Ab = Wb + (size_t)(mb + l15) * CCH + quad * 8;
    const unsigned short* Bb = xT + ((size_t)(b * NN + nb + l15)) * CCH + quad * 8;

    f32x4 C[4][4] = {};
    bf16x8 aA[2][4], bB[2][4];
    #pragma unroll
    for (int i = 0; i < 4; ++i) aA[0][i] = *(const bf16x8*)(Ab + (size_t)(16*i) * CCH);
    #pragma unroll
    for (int j = 0; j < 4; ++j) bB[0][j] = *(const bf16x8*)(Bb + (size_t)(16*j) * CCH);

    #pragma unroll
    for (int kk = 0; kk < 8; ++kk) {
        const int cur = kk & 1;
        if (kk < 7) {
            const int k1 = (kk + 1) * 32;
            #pragma unroll
            for (int i = 0; i < 4; ++i) aA[cur^1][i] = *(const bf16x8*)(Ab + (size_t)(16*i) * CCH + k1);
            #pragma unroll
            for (int j = 0; j < 4; ++j) bB[cur^1][j] = *(const bf16x8*)(Bb + (size_t)(16*j) * CCH + k1);
        }
        #pragma unroll
        for (int i = 0; i < 4; ++i)
            #pragma unroll
            for (int j = 0; j < 4; ++j)
                C[i][j] = MFMA32(aA[cur][i], bB[cur][j], C[i][j]);
    }

    unsigned short* sEw = &sE[wave][0];
    if (mb < 320) {
        // Q or K: transpose to [n][o] rows
        #pragma unroll
        for (int i = 0; i < 4; ++i)
            #pragma unroll
            for (int j = 0; j < 4; ++j) {
                unsigned p01 = bfpair(C[i][j][0], C[i][j][1]);
                unsigned p23 = bfpair(C[i][j][2], C[i][j][3]);
                unsigned short* p = sEw + (16*j + l15) * 72 + 16*i + quad*4;
                *(unsigned*)p = p01;
                *(unsigned*)(p + 2) = p23;
            }
        if (mb < 256) {
            #pragma unroll
            for (int it = 0; it < 8; ++it) {
                int flat = lane + 64 * it;
                int row = flat >> 3;
                int o8  = (flat & 7) * 8;
                uint4 v = *(const uint4*)(sEw + row * 72 + o8);
                *(uint4*)(Qt + ((size_t)(b * NN + nb + row)) * CCH + mb + o8) = v;
            }
        } else {
            #pragma unroll
            for (int it = 0; it < 8; ++it) {
                int flat = lane + 64 * it;
                int row = flat >> 3;
                int o8  = (flat & 7) * 8;
                uint4 v = *(const uint4*)(sEw + row * 72 + o8);
                *(uint4*)(Kt + ((size_t)(b * NN + nb + row)) * 64 + o8) = v;
            }
        }
    } else {
        // V: [d][n] rows
        #pragma unroll
        for (int i = 0; i < 4; ++i)
            #pragma unroll
            for (int j = 0; j < 4; ++j) {
                unsigned p01 = bfpair(C[i][j][0], C[i][j][1]);
                unsigned p23 = bfpair(C[i][j][2], C[i][j][3]);
                unsigned short* p = sEw + (16*i + quad*4) * 72 + 16*j + l15;
                p[0]   = (unsigned short)p01;
                p[72]  = (unsigned short)(p01 >> 16);
                p[144] = (unsigned short)p23;
                p[216] = (unsigned short)(p23 >> 16);
            }
        #pragma unroll
        for (int it = 0; it < 8; ++it) {
            int flat = lane + 64 * it;
            int row = flat >> 3;
            int n8  = (flat & 7) * 8;
            uint4 v = *(const uint4*)(sEw + row * 72 + n8);
            *(uint4*)(Vn + ((size_t)(b * 64 + (mb - 320) + row)) * NN + nb + n8) = v;
        }
    }
}

// ---------------------------------------------------------------------------
// K2: MFMA attention — round-26: EXACT r23 restore (verified 69.5 us).
// Session evidence r17-r25: arithmetic-density changes won (all-MFMA32 +17%,
// deferred-PV +7%); ALL schedule restructures regressed (no-LDS r21 202us:
// LDS staging IS the coalescing engine; 96q-rebalance r22 156us: pf guards
// spill; single-wave r24 137us: 2 waves/CU can't hide in-wave latency;
// wave-parity stagger r25 72.5us: code duplication + post-barrier tail).
// Conclusion: ~70us is this decomposition's chain-latency floor at HIP
// source level. This round locks the verified best; do not touch the
// staging geometry, wave count, or cluster order.
// ---------------------------------------------------------------------------
// element offsets into sKV (unsigned short units):
//   K slots: 0, 4096   (2 x 64x64)
//   V slots: 8192, 12288, 16384   (3 x 64x64)
#define ATT_STEP(STEPN, KCUR, KNXT, VPRV, VNXT, BPP, BPN, DOPV)                  \
    {                                                                            \
        __syncthreads();                                                         \
        if ((STEPN) + 1 < NTILES) {                                              \
            *(bf16x8*)(sKV + (KNXT) + kr0 * 64 + kwc)        = pf[0];            \
            *(bf16x8*)(sKV + (KNXT) + (kr0 + 32) * 64 + kwc) = pf[1];            \
            *(bf16x8*)(sKV + (VNXT) + r0 * 64 + vwc)         = pf[2];            \
            *(bf16x8*)(sKV + (VNXT) + (r0 + 32) * 64 + vwc)  = pf[3];            \
        }                                                                        \
        if ((STEPN) + 2 < NTILES) {                                              \
            const int keys0_ = ((STEPN) + 2) * 64;                               \
            pf[0] = *(const bf16x8*)(Kb + (size_t)keys0_ * 64);                  \
            pf[1] = *(const bf16x8*)(Kb + (size_t)(keys0_ + 32) * 64);           \
            pf[2] = *(const bf16x8*)(Vb + keys0_);                               \
            pf[3] = *(const bf16x8*)(Vb + (size_t)32 * NN + keys0_);             \
        }                                                                        \
        if (DOPV) {                                                              \
            __builtin_amdgcn_s_setprio(1);                                       \
            _Pragma("unroll")                                                    \
            for (int jd_ = 0; jd_ < 4; ++jd_) {                                  \
                _Pragma("unroll")                                                \
                for (int kt2_ = 0; kt2_ < 2; ++kt2_) {                           \
                    const int row_ = 16 * jd_ + l15;                             \
                    const int ch_ = ((4 * kt2_ + quad) ^ (row_ & 7)) * 8;        \
                    bf16x8 aV_ = *(const bf16x8*)(sKV + (VPRV) + row_ * 64 + ch_);\
                    O[jd_][0] = MFMA32(aV_, BPP[kt2_][0], O[jd_][0]);            \
                    O[jd_][1] = MFMA32(aV_, BPP[kt2_][1], O[jd_][1]);            \
                }                                                                \
            }                                                                    \
            dacc[0] = MFMA32(vone8, BPP[0][0], dacc[0]);                         \
            dacc[1] = MFMA32(vone8, BPP[0][1], dacc[1]);                         \
            dacc[0] = MFMA32(vone8, BPP[1][0], dacc[0]);                         \
            dacc[1] = MFMA32(vone8, BPP[1][1], dacc[1]);                         \
            __builtin_amdgcn_s_setprio(0);                                       \
        }                                                                        \
        f32x4 C_[4][2] = {};                                                     \
        __builtin_amdgcn_s_setprio(1);                                           \
        _Pragma("unroll")                                                        \
        for (int s_ = 0; s_ < 2; ++s_) {                                         \
            _Pragma("unroll")                                                    \
            for (int kt_ = 0; kt_ < 4; ++kt_) {                                  \
                const int row_ = 16 * kt_ + l15;                                 \
                const int ch_ = ((s_ * 4 + quad) ^ (row_ & 7)) * 8;              \
                bf16x8 aK_ = *(const bf16x8*)(sKV + (KCUR) + row_ * 64 + ch_);   \
                C_[kt_][0] = MFMA32(aK_, bQ[0][s_], C_[kt_][0]);                 \
                C_[kt_][1] = MFMA32(aK_, bQ[1][s_], C_[kt_][1]);                 \
            }                                                                    \
        }                                                                        \
        __builtin_amdgcn_s_setprio(0);                                           \
        _Pragma("unroll")                                                        \
        for (int kt2_ = 0; kt2_ < 2; ++kt2_) {                                   \
            _Pragma("unroll")                                                    \
            for (int qt_ = 0; qt_ < 2; ++qt_) {                                  \
                union { unsigned u[4]; bf16x8 v; } xp_;                          \
                const f32x4 c0_ = C_[2 * kt2_][qt_];                             \
                const f32x4 c1_ = C_[2 * kt2_ + 1][qt_];                         \
                xp_.u[0] = bfpair(EXP2(c0_[0]), EXP2(c0_[1]));                   \
                xp_.u[1] = bfpair(EXP2(c0_[2]), EXP2(c0_[3]));                   \
                xp_.u[2] = bfpair(EXP2(c1_[0]), EXP2(c1_[1]));                   \
                xp_.u[3] = bfpair(EXP2(c1_[2]), EXP2(c1_[3]));                   \
                BPN[kt2_][qt_] = xp_.v;                                          \
            }                                                                    \
        }                                                                        \
    }

#define ROTV(x) x = ((x) == 16384) ? 8192 : (x) + 4096

__global__ __launch_bounds__(256, 3) void attn_k(
    const unsigned short* __restrict__ Qt,  // [B][N][256]
    const unsigned short* __restrict__ Kt,  // [B][N][64]
    const unsigned short* __restrict__ Vn,  // [B][64][N]
    unsigned short* __restrict__ Ao)        // [B][N][256]
{
    // K dbuf (2x4096 elems) + V tribuf (3x4096 elems) = 20480 shorts = 40 KB
    __shared__ __align__(16) unsigned short sKV[20480];

    const int tid   = threadIdx.x;
    const int wave  = tid >> 6;      // qslot 0..3
    const int lane  = tid & 63;
    const int quad  = lane >> 4;
    const int l15   = lane & 15;
    const int qoff  = wave * 32;
    const int b     = blockIdx.x;
    const int nb    = blockIdx.y * 128;
    const int head  = blockIdx.z;

    const bf16x8 vone8 = {(short)0x3F80, (short)0x3F80, (short)0x3F80, (short)0x3F80,
                          (short)0x3F80, (short)0x3F80, (short)0x3F80, (short)0x3F80};

    // Q fragments (B-operand for S^T): B[n=query][k=d=quad*8+j], 2 q-tiles
    bf16x8 bQ[2][2];
    const unsigned short* QtB = Qt + ((size_t)(b * NN + nb + qoff + l15)) * CCH + head * 64 + quad * 8;
    #pragma unroll
    for (int qt = 0; qt < 2; ++qt)
        #pragma unroll
        for (int s = 0; s < 2; ++s)
            bQ[qt][s] = *(const bf16x8*)(QtB + (size_t)(16*qt) * CCH + s * 32);

    // staging geometry: 256 thr, 2 rows per tile each (rows r0, r0+32)
    const int r0  = tid >> 3;        // 0..31
    const int c8  = (tid & 7) * 8;   // global (unswizzled) column
    // sigma(row): key -> LDS row permutation for K tiles (bit-shuffle
    // b0b1,b3b4,b2,b5 -> row b0..b5) so S^T output tiles land with keys
    // already in MFMA32 B-fragment order (k = quad*8+j) -> lane-local P pack.
    const int kr0 = (r0 & 3) | (((r0 >> 3) & 3) << 2) | (((r0 >> 2) & 1) << 4);
    const int kwc = ((tid & 7) ^ (kr0 & 7)) * 8;   // K write col (both rows)
    const int vwc = ((tid & 7) ^ (r0 & 7)) * 8;    // V write col (both rows)

    const unsigned short* Kb = Kt + ((size_t)(b * NN + r0)) * 64 + c8;
    const unsigned short* Vb = Vn + ((size_t)(b * 64 + r0)) * NN + c8;

    bf16x8 pf[4];
    // step 0 load
    pf[0] = *(const bf16x8*)(Kb);
    pf[1] = *(const bf16x8*)(Kb + (size_t)32 * 64);
    pf[2] = *(const bf16x8*)(Vb);
    pf[3] = *(const bf16x8*)(Vb + (size_t)32 * NN);
    // write step 0 -> K slot0 (@0), V slot0 (@8192)
    *(bf16x8*)(sKV + kr0 * 64 + kwc)               = pf[0];
    *(bf16x8*)(sKV + (kr0 + 32) * 64 + kwc)        = pf[1];
    *(bf16x8*)(sKV + 8192 + r0 * 64 + vwc)         = pf[2];
    *(bf16x8*)(sKV + 8192 + (r0 + 32) * 64 + vwc)  = pf[3];
    // prefetch step 1
    pf[0] = *(const bf16x8*)(Kb + (size_t)64 * 64);
    pf[1] = *(const bf16x8*)(Kb + (size_t)96 * 64);
    pf[2] = *(const bf16x8*)(Vb + 64);
    pf[3] = *(const bf16x8*)(Vb + (size_t)32 * NN + 64);

    f32x4 O[4][2] = {};          // O^T[d-tile jd][q-tile qt]
    f32x4 dacc[2] = {};          // softmax denominators via ones-MFMA
    bf16x8 bPe[2][2], bPo[2][2]; // ping-pong P fragments (even/odd producer)

    // step 0: no deferred PV; stage step1 -> K slot1 (@4096), V slot1 (@12288)
    ATT_STEP(0, 0, 4096, 0 /*unused*/, 12288, bPo /*unused*/, bPe, 0);

    // V-slot rotation state: at step s, VPRV = slot((s-1)%3), VNXT = slot((s+1)%3)
    int vPrv = 8192;    // for step 1: V[0] @ slot0
    int vNxt = 16384;   // for step 1: V[2] -> slot2
    // pairs covering steps 1..34 (17 pairs); odd step uses K slot1, even slot0
    for (int sp = 1; sp < 35; sp += 2) {
        ATT_STEP(sp,     4096, 0,    vPrv, vNxt, bPe, bPo, 1);
        ROTV(vPrv); ROTV(vNxt);
        ATT_STEP(sp + 1, 0,    4096, vPrv, vNxt, bPo, bPe, 1);
        ROTV(vPrv); ROTV(vNxt);
    }
    // step 35 (odd): PV[34] from bPe, produce bPo; no staging/prefetch
    ATT_STEP(35, 4096, 0, vPrv, vNxt, bPe, bPo, 1);
    ROTV(vPrv);   // now = slot(35%3) = V[35]

    // epilogue: deferred PV + denominator for step 35
    __builtin_amdgcn_s_setprio(1);
    #pragma unroll
    for (int jd = 0; jd < 4; ++jd)
        #pragma unroll
        for (int kt2 = 0; kt2 < 2; ++kt2) {
            const int row = 16*jd + l15;
            const int ch  = ((4*kt2 + quad) ^ (row & 7)) * 8;
            bf16x8 aV = *(const bf16x8*)(sKV + vPrv + row * 64 + ch);
            O[jd][0] = MFMA32(aV, bPo[kt2][0], O[jd][0]);
            O[jd][1] = MFMA32(aV, bPo[kt2][1], O[jd][1]);
        }
    dacc[0] = MFMA32(vone8, bPo[0][0], dacc[0]);
    dacc[1] = MFMA32(vone8, bPo[0][1], dacc[1]);
    dacc[0] = MFMA32(vone8, bPo[1][0], dacc[0]);
    dacc[1] = MFMA32(vone8, bPo[1][1], dacc[1]);
    __builtin_amdgcn_s_setprio(0);

    __syncthreads();   // all K/V reads done before sT overlay

    // normalize + transpose to [query][d] rows via LDS
    float rinv[2];
    rinv[0] = 1.0f / dacc[0][0];
    rinv[1] = 1.0f / dacc[1][0];
    unsigned short* sT = (unsigned short*)sKV;   // [128 n][72]
    #pragma unroll
    for (int qt = 0; qt < 2; ++qt)
        #pragma unroll
        for (int jd = 0; jd < 4; ++jd) {
            unsigned lo = bfpair(O[jd][qt][0] * rinv[qt], O[jd][qt][1] * rinv[qt]);
            unsigned hi = bfpair(O[jd][qt][2] * rinv[qt], O[jd][qt][3] * rinv[qt]);
            *(uint2*)(sT + (qoff + 16*qt + l15) * 72 + 16*jd + quad*4) = make_uint2(lo, hi);
        }
    __syncthreads();

    // coalesced writeout: 128 rows x 64 channels = 1024 uint4 chunks
    #pragma unroll
    for (int it = 0; it < 4; ++it) {
        int flat = tid + 256 * it;          // 0..1023
        int row  = flat >> 3;               // 0..127
        int cc8  = (flat & 7) * 8;
        uint4 v = *(const uint4*)(sT + row * 72 + cc8);
        *(uint4*)(Ao + ((size_t)(b * NN + nb + row)) * CCH + head * 64 + cc8) = v;
    }
}

// ---------------------------------------------------------------------------
// K3: proj MFMA GEMM (64x64 pipelined) + per-block BN partials.
// projb[b][c][n] (bf16) = sum_o Pb[c][o]*Ao[b][n][o]+pb[c]
// grid (8 b, 36 ntile, 2 ctile), 128 thr (2 waves).
// ---------------------------------------------------------------------------
__global__ __launch_bounds__(128) void proj_mfma_k(
    const unsigned short* __restrict__ Pb, const unsigned short* __restrict__ Ao,
    const float* __restrict__ pb, unsigned short* __restrict__ projb,
    float* __restrict__ psum, float* __restrict__ psq)
{
    __shared__ unsigned short sE[2][64 * 72];
    const int tid = threadIdx.x;
    const int wave = tid >> 6;
    const int lane = tid & 63;
    const int quad = lane >> 4;
    const int l15  = lane & 15;
    const int b  = blockIdx.x;
    const int nb = blockIdx.y * 64;
    const int mb = blockIdx.z * 128 + wave * 64;
    const int part = b * NTILES + blockIdx.y;   // 0..287

    const unsigned short* Ab = Pb + (size_t)(mb + l15) * CCH + quad * 8;
    const unsigned short* Bb = Ao + ((size_t)(b * NN + nb + l15)) * CCH + quad * 8;

    f32x4 C[4][4] = {};
    bf16x8 aA[2][4], bB[2][4];
    #pragma unroll
    for (int i = 0; i < 4; ++i) aA[0][i] = *(const bf16x8*)(Ab + (size_t)(16*i) * CCH);
    #pragma unroll
    for (int j = 0; j < 4; ++j) bB[0][j] = *(const bf16x8*)(Bb + (size_t)(16*j) * CCH);

    #pragma unroll
    for (int kk = 0; kk < 8; ++kk) {
        const int cur = kk & 1;
        if (kk < 7) {
            const int k1 = (kk + 1) * 32;
            #pragma unroll
            for (int i = 0; i < 4; ++i) aA[cur^1][i] = *(const bf16x8*)(Ab + (size_t)(16*i) * CCH + k1);
            #pragma unroll
            for (int j = 0; j < 4; ++j) bB[cur^1][j] = *(const bf16x8*)(Bb + (size_t)(16*j) * CCH + k1);
        }
        #pragma unroll
        for (int i = 0; i < 4; ++i)
            #pragma unroll
            for (int j = 0; j < 4; ++j)
                C[i][j] = MFMA32(aA[cur][i], bB[cur][j], C[i][j]);
    }

    unsigned short* sEw = &sE[wave][0];
    #pragma unroll
    for (int i = 0; i < 4; ++i) {
        #pragma unroll
        for (int r = 0; r < 4; ++r) {
            const int ch = mb + 16*i + quad*4 + r;
            const float bias = pb[ch];
            float v0 = C[i][0][r] + bias, v1 = C[i][1][r] + bias;
            float v2 = C[i][2][r] + bias, v3 = C[i][3][r] + bias;
            C[i][0][r] = v0; C[i][1][r] = v1; C[i][2][r] = v2; C[i][3][r] = v3;
            float rs = (v0 + v1) + (v2 + v3);
            float rq = (v0*v0 + v1*v1) + (v2*v2 + v3*v3);
            rs += __shfl_xor(rs, 1); rq += __shfl_xor(rq, 1);
            rs += __shfl_xor(rs, 2); rq += __shfl_xor(rq, 2);
            rs += __shfl_xor(rs, 4); rq += __shfl_xor(rq, 4);
            rs += __shfl_xor(rs, 8); rq += __shfl_xor(rq, 8);
            if (l15 == 0) {
                psum[(size_t)ch * NPART + part] = rs;
                psq [(size_t)ch * NPART + part] = rq;
            }
        }
    }

    // bf16 output via LDS transpose: rows = c_local, cols = n
    #pragma unroll
    for (int i = 0; i < 4; ++i)
        #pragma unroll
        for (int j = 0; j < 4; ++j) {
            unsigned p01 = bfpair(C[i][j][0], C[i][j][1]);
            unsigned p23 = bfpair(C[i][j][2], C[i][j][3]);
            unsigned short* p = sEw + (16*i + quad*4) * 72 + 16*j + l15;
            p[0]   = (unsigned short)p01;
            p[72]  = (unsigned short)(p01 >> 16);
            p[144] = (unsigned short)p23;
            p[216] = (unsigned short)(p23 >> 16);
        }
    #pragma unroll
    for (int it = 0; it < 8; ++it) {
        int flat = lane + 64 * it;
        int row = flat >> 3;                // c local
        int n8  = (flat & 7) * 8;
        uint4 v = *(const uint4*)(sEw + row * 72 + n8);
        *(uint4*)(projb + ((size_t)(b * CCH + mb + row)) * NN + nb + n8) = v;
    }
}

// ---------------------------------------------------------------------------
// K4: fused BN finalize + apply. grid (8 b, 256 c), 256 thr.
// out = scale[c]*projb + shift[c] + x   (projb bf16, x fp32; out fp32)
// r25 (verified): stats via wave shuffle; residual read directly from x.
// ---------------------------------------------------------------------------
__global__ __launch_bounds__(256) void bn_apply_k(
    const unsigned short* __restrict__ projb, const float* __restrict__ x,
    const float* __restrict__ psum, const float* __restrict__ psq,
    const float* __restrict__ gamma, const float* __restrict__ beta,
    float* __restrict__ out)
{
    const int tid = threadIdx.x;
    const int b = blockIdx.x;
    const int c = blockIdx.y;

    float s = 0.f, q = 0.f;
    for (int k = tid; k < NPART; k += 256) {
        s += psum[(size_t)c * NPART + k];
        q += psq [(size_t)c * NPART + k];
    }
    // wave-level butterfly, then 4 wave-partials summed by every thread
    #pragma unroll
    for (int off = 32; off > 0; off >>= 1) {
        s += __shfl_xor(s, off);
        q += __shfl_xor(q, off);
    }
    __shared__ float ws[8];
    if ((tid & 63) == 0) { ws[tid >> 6] = s; ws[4 + (tid >> 6)] = q; }
    __syncthreads();
    const float S = (ws[0] + ws[1]) + (ws[2] + ws[3]);
    const float Q = (ws[4] + ws[5]) + (ws[6] + ws[7]);

    const float inv_n = 1.0f / (float)(BB * NN);
    float mean = S * inv_n;
    float var  = Q * inv_n - mean * mean;
    float scv = gamma[c] * rsqrtf(var + BN_EPS);
    float shv = beta[c] - mean * scv;

    #pragma unroll
    for (int it = 0; it < 2; ++it) {
        int chunk = tid + 256 * it;
        if (chunk < 288) {
            size_t base = ((size_t)(b * CCH + c)) * NN + chunk * 8;
            uint4 pv = *(const uint4*)(projb + base);
            float4 xv0 = *(const float4*)(x + base);
            float4 xv1 = *(const float4*)(x + base + 4);
            const unsigned short* pp = (const unsigned short*)&pv;
            float4 r0, r1;
            r0.x = scv * bf2f(pp[0]) + shv + xv0.x;
            r0.y = scv * bf2f(pp[1]) + shv + xv0.y;
            r0.z = scv * bf2f(pp[2]) + shv + xv0.z;
            r0.w = scv * bf2f(pp[3]) + shv + xv0.w;
            r1.x = scv * bf2f(pp[4]) + shv + xv1.x;
            r1.y = scv * bf2f(pp[5]) + shv + xv1.y;
            r1.z = scv * bf2f(pp[6]) + shv + xv1.z;
            r1.w = scv * bf2f(pp[7]) + shv + xv1.w;
            *(float4*)(out + base) = r0;
            *(float4*)(out + base + 4) = r1;
        }
    }
}

extern "C" void kernel_launch(void* const* d_in, const int* in_sizes, int n_in,
                              void* d_out, int out_size, void* d_ws, size_t ws_size,
                              hipStream_t stream)
{
    const float* x     = (const float*)d_in[0];
    const float* qw    = (const float*)d_in[1];
    const float* kw    = (const float*)d_in[2];
    const float* vw    = (const float*)d_in[3];
    const float* pw    = (const float*)d_in[4];
    const float* pb    = (const float*)d_in[5];
    const float* gamma = (const float*)d_in[6];
    const float* beta  = (const float*)d_in[7];
    float* out = (float*)d_out;

    char* ws = (char*)d_ws;
    // Ao overlays xT (dead after K1); projb overlays Qt (dead after K2).
    unsigned short* xT = (unsigned short*)ws;                       //  9,437,184
    unsigned short* Ao = (unsigned short*)ws;                       //  overlay
    unsigned short* Wb = (unsigned short*)(ws + 9437184);           //    196,608
    unsigned short* Pb = (unsigned short*)(ws + 9633792);           //    131,072
    unsigned short* Qt = (unsigned short*)(ws + 9764864);           //  9,437,184
    unsigned short* Kt = (unsigned short*)(ws + 19202048);          //  2,359,296
    unsigned short* Vn = (unsigned short*)(ws + 21561344);          //  2,359,296
    unsigned short* projb = (unsigned short*)(ws + 9764864);        //  overlay (9.4 MB)
    float* psum  = (float*)(ws + 28639232);                         //    294,912
    float* psq   = (float*)(ws + 28934144);                         //    294,912

    prep_k<<<1792, 256, 0, stream>>>(x, qw, kw, vw, pw, xT, Wb, Pb);

    dim3 g1(BB, NN / 64, 3);
    qkv_mfma_k<<<g1, 128, 0, stream>>>(Wb, xT, Qt, Kt, Vn);

    dim3 g2(BB, NN / 128, NH);
    attn_k<<<g2, 256, 0, stream>>>(Qt, Kt, Vn, Ao);

    dim3 g3(BB, NN / 64, 2);
    proj_mfma_k<<<g3, 128, 0, stream>>>(Pb, Ao, pb, projb, psum, psq);

    dim3 g4(BB, CCH);
    bn_apply_k<<<g4, 256, 0, stream>>>(projb, x, psum, psq, gamma, beta, out);
}